// Round 1
// baseline (2735.392 us; speedup 1.0000x reference)
//
#include <hip/hip_runtime.h>
#include <hip/hip_bf16.h>

// Problem constants (B=32, T=64, S=64, H=512, E=256, V_OUT=32000, L=2)
// Output 0: log_probs [32,64,32000] = 65,536,000 f32; Output 1: h_out [2,32,512] = 32,768 f32.
// targets_len (d_in[3]) is unused by the reference.

#define DEV __device__ __forceinline__

typedef unsigned short u16;
typedef __attribute__((ext_vector_type(8))) short short8;
typedef __attribute__((ext_vector_type(4))) float f32x4;
typedef __attribute__((ext_vector_type(4))) unsigned short u16x4;

DEV u16 f2bf(float f) {
  unsigned u = __float_as_uint(f);
  u += 0x7FFFu + ((u >> 16) & 1u);   // round-to-nearest-even
  return (u16)(u >> 16);
}
DEV float bfu(u16 u) { return __uint_as_float(((unsigned)u) << 16); }
DEV float sigm(float x) { return 1.f / (1.f + __expf(-x)); }

DEV void store_out(float* p, float v) { *p = v; }
DEV void store_out(u16* p, float v) { *p = f2bf(v); }

#define GLD_LDS(g, l) \
  __builtin_amdgcn_global_load_lds((const __attribute__((address_space(1))) void*)(g), \
                                   (__attribute__((address_space(3))) void*)(l), 16, 0, 0)

// ---------------------------------------------------------------------------
// Generic C = A @ B^T GEMM, bf16 inputs, fp32 accum. A [M,K], Bw [N,K] row-major.
// 128x128 tile, BK=64, 4 waves (each a 64x64 quadrant of 4x4 16x16x32 frags).
// ACT: 0=none, 1=tanh. bias (len N) optional. M,N mult of 128; K mult of 64.
// ---------------------------------------------------------------------------
template<int ACT, typename OutT>
__global__ __launch_bounds__(256)
void gemm_bt(const u16* __restrict__ A, const u16* __restrict__ Bw,
             const float* __restrict__ bias, OutT* __restrict__ C,
             int M, int N, int K) {
  __shared__ __align__(16) u16 As[128 * 64];
  __shared__ __align__(16) u16 Bs[128 * 64];
  const int tid  = threadIdx.x;
  const int wave = tid >> 6;
  const int lane = tid & 63;
  const int mBase = blockIdx.x * 128;
  const int nBase = blockIdx.y * 128;
  const int wr = wave >> 1, wc = wave & 1;

  f32x4 acc[4][4] = {};

  const int srow = lane >> 3;        // 0..7 within 8-row slot
  const int scol = (lane & 7) * 8;   // element col within 64

  for (int k0 = 0; k0 < K; k0 += 64) {
#pragma unroll
    for (int j = 0; j < 4; ++j) {
      const int slot = wave * 4 + j;           // 0..15 -> rows slot*8..+8
      const int row  = slot * 8 + srow;
      const u16* ga = A  + (size_t)(mBase + row) * K + k0 + scol;
      GLD_LDS(ga, &As[slot * 512]);
      const u16* gb = Bw + (size_t)(nBase + row) * K + k0 + scol;
      GLD_LDS(gb, &Bs[slot * 512]);
    }
    __syncthreads();   // waits vmcnt(0): staged tile complete
#pragma unroll
    for (int ks = 0; ks < 2; ++ks) {
      const int kb = ks * 32 + (lane >> 4) * 8;
      short8 a[4], b[4];
#pragma unroll
      for (int i = 0; i < 4; ++i) {
        a[i] = *(const short8*)&As[(wr * 64 + i * 16 + (lane & 15)) * 64 + kb];
        b[i] = *(const short8*)&Bs[(wc * 64 + i * 16 + (lane & 15)) * 64 + kb];
      }
#pragma unroll
      for (int mi = 0; mi < 4; ++mi)
#pragma unroll
        for (int ni = 0; ni < 4; ++ni)
          acc[mi][ni] = __builtin_amdgcn_mfma_f32_16x16x32_bf16(a[mi], b[ni], acc[mi][ni], 0, 0, 0);
    }
    __syncthreads();   // before restaging
  }

  // Epilogue: C/D layout col = lane&15, row = (lane>>4)*4 + reg (m89-verified)
#pragma unroll
  for (int mi = 0; mi < 4; ++mi) {
    const int row = mBase + wr * 64 + mi * 16 + (lane >> 4) * 4;
#pragma unroll
    for (int ni = 0; ni < 4; ++ni) {
      const int col = nBase + wc * 64 + ni * 16 + (lane & 15);
      const float bv = bias ? bias[col] : 0.f;
#pragma unroll
      for (int r = 0; r < 4; ++r) {
        float x = acc[mi][ni][r] + bv;
        if (ACT == 1) x = tanhf(x);
        store_out(&C[(size_t)(row + r) * N + col], x);
      }
    }
  }
}

// ---------------------------------------------------------------------------
// LSTM recurrence: 32 persistent blocks (co-resident; 1/CU), 512 threads each.
// Block g owns h-slice k0=g*16..+16 (i.e. W_hh rows {gate*512+k0+kk}).
// W_hh slice lives in LDS (bf16, 64 KB). Per step: gates_h = h @ Whh_slice^T via
// MFMA, add precomputed gates_x, elementwise LSTM update, publish h (bf16) to
// global, device-scope barrier, reload full h into LDS.
// ---------------------------------------------------------------------------
__global__ __launch_bounds__(512)
void lstm_rec(const float* __restrict__ Whh,   // [2048][512] f32
              const float* __restrict__ gx,    // [2048][2048] f32 (m = b*64+t)
              const float* __restrict__ h0,    // [32][512] f32
              u16* __restrict__ hseq,          // [32][64][512] bf16 out
              float* __restrict__ hT,          // [32][512] f32 (d_out tail)
              unsigned* __restrict__ bar) {    // 64 zeroed counters
  __shared__ __align__(16) u16 Ws[64 * 512];   // rows: n = gate*16+kk
  __shared__ __align__(16) u16 Hs[32 * 512];
  __shared__ float Cs[512];
  __shared__ float Gs[32 * 64];
  const int tid  = threadIdx.x;
  const int wave = tid >> 6, lane = tid & 63;
  const int k0 = blockIdx.x * 16;

  for (int i = tid; i < 64 * 512; i += 512) {
    const int lr = i >> 9, c = i & 511;
    const int grow = ((lr >> 4) * 512) + k0 + (lr & 15);
    Ws[i] = f2bf(Whh[(size_t)grow * 512 + c]);
  }
  for (int i = tid; i < 32 * 512; i += 512) Hs[i] = f2bf(h0[i]);
  Cs[tid] = 0.f;
  __syncthreads();

  const int mi = wave & 1;   // m-tile (batch rows 16*mi..)
  const int ni = wave >> 1;  // n-tile == gate index

  for (int t = 0; t < 64; ++t) {
    f32x4 acc = {0.f, 0.f, 0.f, 0.f};
#pragma unroll
    for (int ks = 0; ks < 16; ++ks) {
      const int kb = ks * 32 + (lane >> 4) * 8;
      short8 a = *(const short8*)&Hs[(mi * 16 + (lane & 15)) * 512 + kb];
      short8 b = *(const short8*)&Ws[(ni * 16 + (lane & 15)) * 512 + kb];
      acc = __builtin_amdgcn_mfma_f32_16x16x32_bf16(a, b, acc, 0, 0, 0);
    }
    {
      const int gr = mi * 16 + (lane >> 4) * 4;
      const int gc = ni * 16 + (lane & 15);
#pragma unroll
      for (int r = 0; r < 4; ++r) Gs[(gr + r) * 64 + gc] = acc[r];
    }
    __syncthreads();
    {
      const int b  = tid >> 4, kk = tid & 15;
      const float* g = gx + (size_t)(b * 64 + t) * 2048 + k0 + kk;
      const float gi = Gs[b * 64 +  0 + kk] + g[0];
      const float gf = Gs[b * 64 + 16 + kk] + g[512];
      const float gg = Gs[b * 64 + 32 + kk] + g[1024];
      const float go = Gs[b * 64 + 48 + kk] + g[1536];
      const float c  = sigm(gf) * Cs[tid] + sigm(gi) * tanhf(gg);
      const float h  = sigm(go) * tanhf(c);
      Cs[tid] = c;
      hseq[(size_t)(b * 64 + t) * 512 + k0 + kk] = f2bf(h);
      if (t == 63) hT[b * 512 + k0 + kk] = h;
    }
    if (t < 63) {
      __threadfence();
      __syncthreads();
      if (tid == 0) {
        __hip_atomic_fetch_add(bar + t, 1u, __ATOMIC_ACQ_REL, __HIP_MEMORY_SCOPE_AGENT);
        while (__hip_atomic_load(bar + t, __ATOMIC_ACQUIRE, __HIP_MEMORY_SCOPE_AGENT) < 32u)
          __builtin_amdgcn_s_sleep(1);
      }
      __syncthreads();
      __threadfence();
      for (int i = tid * 8; i < 32 * 512; i += 512 * 8) {
        const int b = i >> 9, k = i & 511;
        *(short8*)&Hs[i] = *(const short8*)&hseq[(size_t)(b * 64 + t) * 512 + k];
      }
      __syncthreads();
    }
  }
}

// ---------------------------------------------------------------------------
// Attention: per (t-chunk of 16, batch b): scores = out_tile @ proj_b^T,
// softmax over S=64, context = attn @ enc_b; writes h_c = [out | context] bf16.
// ---------------------------------------------------------------------------
__global__ __launch_bounds__(256)
void attn_ctx(const u16* __restrict__ outSeq,  // [32][64][512] bf16
              const u16* __restrict__ proj,    // [32][64][512] bf16
              const u16* __restrict__ enc,     // [32][64][1024] bf16
              u16* __restrict__ h_c) {         // [2048][1536] bf16
  __shared__ __align__(16) u16 proj_s[64 * 512];
  __shared__ __align__(16) u16 out_s[16 * 512];
  __shared__ float attn_s[16 * 64];
  const int tid = threadIdx.x;
  const int tq = blockIdx.x;   // 0..3
  const int b  = blockIdx.y;   // 0..31

  for (int i = tid * 8; i < 64 * 512; i += 256 * 8)
    *(short8*)&proj_s[i] = *(const short8*)&proj[(size_t)b * 64 * 512 + i];
  for (int i = tid * 8; i < 16 * 512; i += 256 * 8)
    *(short8*)&out_s[i] = *(const short8*)&outSeq[((size_t)b * 64 + tq * 16) * 512 + i];
  __syncthreads();

  {
    const int tl = tid >> 4;   // local t row 0..15
    const int sg = tid & 15;   // s group: s = sg*4 + ss
    float acc[4] = {0.f, 0.f, 0.f, 0.f};
    for (int k = 0; k < 512; k += 8) {
      const short8 av = *(const short8*)&out_s[tl * 512 + k];
      float af[8];
#pragma unroll
      for (int j = 0; j < 8; ++j) af[j] = bfu((u16)av[j]);
#pragma unroll
      for (int ss = 0; ss < 4; ++ss) {
        const short8 bv = *(const short8*)&proj_s[(sg * 4 + ss) * 512 + k];
        float d0 = 0.f;
#pragma unroll
        for (int j = 0; j < 8; ++j) d0 += af[j] * bfu((u16)bv[j]);
        acc[ss] += d0;
      }
    }
    float mx = fmaxf(fmaxf(acc[0], acc[1]), fmaxf(acc[2], acc[3]));
#pragma unroll
    for (int o = 1; o < 16; o <<= 1) mx = fmaxf(mx, __shfl_xor(mx, o));
    const float p0 = __expf(acc[0] - mx), p1 = __expf(acc[1] - mx);
    const float p2 = __expf(acc[2] - mx), p3 = __expf(acc[3] - mx);
    float s = p0 + p1 + p2 + p3;
#pragma unroll
    for (int o = 1; o < 16; o <<= 1) s += __shfl_xor(s, o);
    const float inv = 1.f / s;
    attn_s[tl * 64 + sg * 4 + 0] = p0 * inv;
    attn_s[tl * 64 + sg * 4 + 1] = p1 * inv;
    attn_s[tl * 64 + sg * 4 + 2] = p2 * inv;
    attn_s[tl * 64 + sg * 4 + 3] = p3 * inv;
  }
  __syncthreads();

  {
    const int c4 = tid * 4;   // context col base (0..1020)
    for (int tc = 0; tc < 16; tc += 4) {
      float a[4][4] = {};
      for (int s = 0; s < 64; ++s) {
        const u16x4 ev = *(const u16x4*)&enc[((size_t)b * 64 + s) * 1024 + c4];
        const float e0 = bfu(ev[0]), e1 = bfu(ev[1]), e2 = bfu(ev[2]), e3 = bfu(ev[3]);
#pragma unroll
        for (int r = 0; r < 4; ++r) {
          const float w = attn_s[(tc + r) * 64 + s];
          a[r][0] += w * e0; a[r][1] += w * e1; a[r][2] += w * e2; a[r][3] += w * e3;
        }
      }
#pragma unroll
      for (int r = 0; r < 4; ++r) {
        const size_t rowp = ((size_t)b * 64 + tq * 16 + tc + r) * 1536 + 512 + c4;
        h_c[rowp + 0] = f2bf(a[r][0]);
        h_c[rowp + 1] = f2bf(a[r][1]);
        h_c[rowp + 2] = f2bf(a[r][2]);
        h_c[rowp + 3] = f2bf(a[r][3]);
      }
    }
    for (int i = tid * 8; i < 16 * 512; i += 256 * 8) {
      const int r = i >> 9, k = i & 511;
      *(short8*)&h_c[((size_t)b * 64 + tq * 16 + r) * 1536 + k] = *(const short8*)&out_s[i];
    }
  }
}

// ---------------------------------------------------------------------------
// Small helper kernels
// ---------------------------------------------------------------------------
__global__ __launch_bounds__(256)
void cvt_bf16(const float* __restrict__ in, u16* __restrict__ out, int n4) {
  int i = blockIdx.x * 256 + threadIdx.x;
  const int stride = gridDim.x * 256;
  for (; i < n4; i += stride) {
    const float4 v = ((const float4*)in)[i];
    u16x4 o; o[0] = f2bf(v.x); o[1] = f2bf(v.y); o[2] = f2bf(v.z); o[3] = f2bf(v.w);
    ((u16x4*)out)[i] = o;
  }
}

__global__ __launch_bounds__(256)
void bias_sum(const float* __restrict__ a, const float* __restrict__ b,
              float* __restrict__ o, int n) {
  const int i = blockIdx.x * 256 + threadIdx.x;
  if (i < n) o[i] = a[i] + b[i];
}

__global__ __launch_bounds__(256)
void gather_emb(const int* __restrict__ ids, const float* __restrict__ emb,
                u16* __restrict__ x) {
  const int i4 = blockIdx.x * 256 + threadIdx.x;   // 131072 total
  if (i4 >= 2048 * 64) return;
  const int row = i4 >> 6;          // token index (b*64+t)
  const int c4  = i4 & 63;
  const int id  = ids[row];
  const float4 v = ((const float4*)emb)[(size_t)id * 64 + c4];
  u16x4 o; o[0] = f2bf(v.x); o[1] = f2bf(v.y); o[2] = f2bf(v.z); o[3] = f2bf(v.w);
  ((u16x4*)x)[i4] = o;
}

__global__ __launch_bounds__(256)
void row_lse(const float* __restrict__ logits, float* __restrict__ lse) {
  const int m = blockIdx.x;
  const float* row = logits + (size_t)m * 32000;
  const int tid = threadIdx.x;
  const int wave = tid >> 6, lane = tid & 63;
  __shared__ float red[4];

  float mx = -3.4e38f;
  for (int i = tid; i < 8000; i += 256) {
    const float4 v = ((const float4*)row)[i];
    mx = fmaxf(fmaxf(fmaxf(mx, v.x), v.y), fmaxf(v.z, v.w));
  }
#pragma unroll
  for (int o = 1; o < 64; o <<= 1) mx = fmaxf(mx, __shfl_xor(mx, o));
  if (lane == 0) red[wave] = mx;
  __syncthreads();
  mx = fmaxf(fmaxf(red[0], red[1]), fmaxf(red[2], red[3]));

  float s = 0.f;
  for (int i = tid; i < 8000; i += 256) {
    const float4 v = ((const float4*)row)[i];
    s += __expf(v.x - mx) + __expf(v.y - mx) + __expf(v.z - mx) + __expf(v.w - mx);
  }
#pragma unroll
  for (int o = 1; o < 64; o <<= 1) s += __shfl_xor(s, o);
  __syncthreads();
  if (lane == 0) red[wave] = s;
  __syncthreads();
  if (tid == 0) lse[m] = mx + logf(red[0] + red[1] + red[2] + red[3]);
}

__global__ __launch_bounds__(256)
void sub_lse(float* __restrict__ out, const float* __restrict__ lse) {
  size_t i = (size_t)blockIdx.x * 256 + threadIdx.x;
  const size_t n4 = 16384000;   // 65,536,000 / 4
  const size_t stride = (size_t)gridDim.x * 256;
  for (; i < n4; i += stride) {
    float4 v = ((float4*)out)[i];
    const unsigned row = (unsigned)i / 8000u;   // 8000 float4 per 32000-col row
    const float s = lse[row];
    v.x -= s; v.y -= s; v.z -= s; v.w -= s;
    ((float4*)out)[i] = v;
  }
}

// ---------------------------------------------------------------------------
extern "C" void kernel_launch(void* const* d_in, const int* in_sizes, int n_in,
                              void* d_out, int out_size, void* d_ws, size_t ws_size,
                              hipStream_t stream) {
  (void)in_sizes; (void)n_in; (void)out_size; (void)ws_size;
  const int*   ids   = (const int*)  d_in[0];
  const float* encf  = (const float*)d_in[1];
  const float* hinit = (const float*)d_in[2];
  // d_in[3] = targets_len: unused by the reference
  const float* emb   = (const float*)d_in[4];
  const float* Wih0  = (const float*)d_in[5];
  const float* Whh0  = (const float*)d_in[6];
  const float* bih0  = (const float*)d_in[7];
  const float* bhh0  = (const float*)d_in[8];
  const float* Wih1  = (const float*)d_in[9];
  const float* Whh1  = (const float*)d_in[10];
  const float* bih1  = (const float*)d_in[11];
  const float* bhh1  = (const float*)d_in[12];
  const float* Wattn = (const float*)d_in[13];
  const float* Wl1   = (const float*)d_in[14];
  const float* Wl2   = (const float*)d_in[15];

  char* ws = (char*)d_ws;
  size_t off = 0;
  auto alloc = [&](size_t bytes) -> void* {
    void* p = ws + off;
    off += (bytes + 255) & ~(size_t)255;
    return p;
  };
  u16*   Wih0b = (u16*)  alloc((size_t)2048 * 256 * 2);
  u16*   Wih1b = (u16*)  alloc((size_t)2048 * 512 * 2);
  u16*   Wattb = (u16*)  alloc((size_t)512 * 1024 * 2);
  u16*   Wl1b  = (u16*)  alloc((size_t)512 * 1536 * 2);
  u16*   Wl2b  = (u16*)  alloc((size_t)32000 * 512 * 2);
  u16*   encb  = (u16*)  alloc((size_t)2048 * 1024 * 2);
  u16*   xb    = (u16*)  alloc((size_t)2048 * 256 * 2);
  float* gates = (float*)alloc((size_t)2048 * 2048 * 4);
  u16*   h1s   = (u16*)  alloc((size_t)2048 * 512 * 2);
  u16*   outs  = (u16*)  alloc((size_t)2048 * 512 * 2);
  u16*   projb = (u16*)  alloc((size_t)2048 * 512 * 2);
  u16*   hcb   = (u16*)  alloc((size_t)2048 * 1536 * 2);
  u16*   zb    = (u16*)  alloc((size_t)2048 * 512 * 2);
  float* lse   = (float*)alloc((size_t)2048 * 4);
  float* bias0 = (float*)alloc((size_t)2048 * 4);
  float* bias1 = (float*)alloc((size_t)2048 * 4);
  unsigned* bar = (unsigned*)alloc(128 * 4);

  float* logp = (float*)d_out;                 // [2048][32000]
  float* hTout = logp + (size_t)65536000;      // [2][32][512]

  hipMemsetAsync(bar, 0, 128 * 4, stream);

  // weight / input conversions to bf16
  auto cvt = [&](const float* in, u16* out, size_t n) {
    const int n4 = (int)(n / 4);
    int grid = (n4 + 255) / 256; if (grid > 2048) grid = 2048;
    cvt_bf16<<<grid, 256, 0, stream>>>(in, out, n4);
  };
  cvt(Wih0,  Wih0b, (size_t)2048 * 256);
  cvt(Wih1,  Wih1b, (size_t)2048 * 512);
  cvt(Wattn, Wattb, (size_t)512 * 1024);
  cvt(Wl1,   Wl1b,  (size_t)512 * 1536);
  cvt(Wl2,   Wl2b,  (size_t)32000 * 512);
  cvt(encf,  encb,  (size_t)2048 * 1024);
  bias_sum<<<8, 256, 0, stream>>>(bih0, bhh0, bias0, 2048);
  bias_sum<<<8, 256, 0, stream>>>(bih1, bhh1, bias1, 2048);
  gather_emb<<<512, 256, 0, stream>>>(ids, emb, xb);

  // layer 0: x-part gates, then recurrence
  gemm_bt<0, float><<<dim3(16, 16), 256, 0, stream>>>(xb, Wih0b, bias0, gates, 2048, 2048, 256);
  lstm_rec<<<32, 512, 0, stream>>>(Whh0, gates, hinit, h1s, hTout, bar);

  // layer 1
  gemm_bt<0, float><<<dim3(16, 16), 256, 0, stream>>>(h1s, Wih1b, bias1, gates, 2048, 2048, 512);
  lstm_rec<<<32, 512, 0, stream>>>(Whh1, gates, hinit + 32 * 512, outs, hTout + 32 * 512, bar + 64);

  // attention
  gemm_bt<0, u16><<<dim3(16, 4), 256, 0, stream>>>(encb, Wattb, nullptr, projb, 2048, 512, 1024);
  attn_ctx<<<dim3(4, 32), 256, 0, stream>>>(outs, projb, encb, hcb);

  // output head
  gemm_bt<1, u16><<<dim3(16, 4), 256, 0, stream>>>(hcb, Wl1b, nullptr, zb, 2048, 512, 1536);
  gemm_bt<0, float><<<dim3(16, 250), 256, 0, stream>>>(zb, Wl2b, nullptr, logp, 2048, 32000, 512);
  row_lse<<<2048, 256, 0, stream>>>(logp, lse);
  sub_lse<<<4096, 256, 0, stream>>>(logp, lse);
}